// Round 2
// baseline (1307.095 us; speedup 1.0000x reference)
//
#include <hip/hip_runtime.h>
#include <math.h>

#define NIMG 16
#define A_ 3
#define H_ 160
#define W_ 160
#define C_ 80
#define HW_ (H_*W_)        // 25600
#define P_ (HW_*A_)        // 76800
#define K1 4096
#define K2 300
#define CAND_CAP 8192
#define IMGMAX 639.0f
#define BBOX_CLIP 4.135166556742356f  // log(1000/16)

// ---- orderable key for float (descending by value == descending by key) ----
__device__ __forceinline__ unsigned int f2key(float x) {
    unsigned int u = __float_as_uint(x);
    return (u & 0x80000000u) ? ~u : (u | 0x80000000u);
}
__device__ __forceinline__ float key2f(unsigned int k) {
    unsigned int u = (k & 0x80000000u) ? (k & 0x7FFFFFFFu) : ~k;
    return __uint_as_float(u);
}

// =====================================================================
// S1: global per-image histogram of top-12 key bits (full-chip)
// =====================================================================
__global__ __launch_bounds__(256) void k_hist(
        const float* __restrict__ obj, unsigned int* __restrict__ hist) {
    const int stride = gridDim.x * 256;
    for (int idx = blockIdx.x * 256 + threadIdx.x; idx < NIMG * P_; idx += stride) {
        const int n = idx / P_;
        unsigned int k = f2key(obj[idx]);
        atomicAdd(&hist[n * 4096 + (k >> 20)], 1u);
    }
}

// =====================================================================
// S2: per-image threshold bucket via wave suffix-scan. 16 blocks x 64.
// =====================================================================
__global__ __launch_bounds__(64) void k_thresh(
        const unsigned int* __restrict__ hist, unsigned int* __restrict__ Tarr) {
    const int n = blockIdx.x, lane = threadIdx.x;
    const unsigned int* h = hist + n * 4096;
    unsigned int s = 0;
    for (int m = 0; m < 64; ++m) s += h[lane * 64 + m];
    unsigned int t = s;                       // inclusive suffix sum of chunk sums
    for (int off = 1; off < 64; off <<= 1) {
        unsigned int u = __shfl_down(t, off);
        if (lane + off < 64) t += u;
    }
    bool cond = (t >= (unsigned)K1) && (t - s < (unsigned)K1);
    unsigned long long bal = __ballot(cond);
    int cs = __builtin_ctzll(bal);
    unsigned int suf = __shfl(t - s, cs);     // count strictly above chunk cs
    unsigned int h2 = h[cs * 64 + lane];
    unsigned int t2 = h2;
    for (int off = 1; off < 64; off <<= 1) {
        unsigned int u = __shfl_down(t2, off);
        if (lane + off < 64) t2 += u;
    }
    bool cond2 = (suf + t2 >= (unsigned)K1) && (suf + t2 - h2 < (unsigned)K1);
    if (cond2) Tarr[n] = ((unsigned int)(cs * 64 + lane)) << 20;
}

// =====================================================================
// S3: compaction of keys >= T[n], wave-aggregated atomics. 1200 x 1024.
// stores ~key in high 32 (ascending sort => key desc), idx low 32 (tie asc)
// =====================================================================
__global__ __launch_bounds__(1024) void k_compact(
        const float* __restrict__ obj, const unsigned int* __restrict__ Tarr,
        unsigned long long* __restrict__ cand, unsigned int* __restrict__ cnt) {
    const int n = blockIdx.x / 75;
    const int q = (blockIdx.x % 75) * 1024 + threadIdx.x;   // [0, 76800)
    const unsigned int T = Tarr[n];
    unsigned int k = f2key(obj[(size_t)n * P_ + q]);
    bool pred = (k >= T);
    unsigned long long m = __ballot(pred);
    if (pred) {
        const int lane = threadIdx.x & 63;
        int before = __popcll(m & ((1ull << lane) - 1ull));
        int leader = __builtin_ctzll(m);
        unsigned int base = 0;
        if (lane == leader) base = atomicAdd(&cnt[n], (unsigned int)__popcll(m));
        base = __shfl(base, leader);
        unsigned int pos = base + before;
        if (pos < CAND_CAP) {
            unsigned int p = (unsigned int)((q % HW_) * A_ + (q / HW_));
            cand[(size_t)n * CAND_CAP + pos] =
                ((unsigned long long)(~k) << 32) | (unsigned long long)p;
        }
    }
}

// =====================================================================
// K_sort: per-image bitonic sort (ascending on ~key|idx == key desc, idx asc)
// =====================================================================
__global__ __launch_bounds__(1024) void k_sort(
        const unsigned long long* __restrict__ cand,
        const unsigned int* __restrict__ cnt,
        unsigned int* __restrict__ sidx, float* __restrict__ sscore) {
    const int n = blockIdx.x;
    __shared__ unsigned long long S[CAND_CAP];   // 64 KB
    const int tid = threadIdx.x;
    unsigned int c = cnt[n]; if (c > CAND_CAP) c = CAND_CAP;
    for (int t = tid; t < CAND_CAP; t += 1024)
        S[t] = (t < (int)c) ? cand[(size_t)n * CAND_CAP + t] : 0xFFFFFFFFFFFFFFFFull;
    __syncthreads();
    for (int k = 2; k <= CAND_CAP; k <<= 1) {
        for (int j = k >> 1; j > 0; j >>= 1) {
            for (int t = tid; t < CAND_CAP; t += 1024) {
                int ixj = t ^ j;
                if (ixj > t) {
                    unsigned long long a = S[t], b = S[ixj];
                    bool up = ((t & k) == 0);
                    if ((a > b) == up) { S[t] = b; S[ixj] = a; }
                }
            }
            __syncthreads();
        }
    }
    for (int t = tid; t < K1; t += 1024) {
        unsigned long long s = S[t];
        sidx[(size_t)n * K1 + t] = (unsigned int)s;
        float x = key2f(~(unsigned int)(s >> 32));
        sscore[(size_t)n * K1 + t] = 1.0f / (1.0f + expf(-x));
    }
}

// =====================================================================
// K_decode: analytic anchors + box decode + clip. 65536 threads.
// =====================================================================
__global__ __launch_bounds__(256) void k_decode(
        const unsigned int* __restrict__ sidx, const float* __restrict__ reg,
        float* __restrict__ bx1, float* __restrict__ by1,
        float* __restrict__ bx2, float* __restrict__ by2) {
#pragma clang fp contract(off)
    const int gid = blockIdx.x * 256 + threadIdx.x;
    const int n = gid >> 12;
    const unsigned int p = sidx[gid];
    const int a  = (int)(p % 3u);
    const int hw = (int)(p / 3u);
    const int hh = hw / W_, ww = hw % W_;

    const float* rb = reg + ((size_t)n * 12 + a * 4) * HW_ + hw;
    float dx = rb[0];
    float dy = rb[HW_];
    float dw = rb[2 * HW_];
    float dh = rb[3 * HW_];

    // analytic anchors — exact integers, bit-identical to reference setup
    const int half = 16 << a;
    float a0 = (float)(4 * ww + 2 - half);
    float a1 = (float)(4 * hh + 2 - half);
    float a2 = (float)(4 * ww + 2 + half - 1);
    float a3 = (float)(4 * hh + 2 + half - 1);

    float w  = a2 - a0 + 1.0f;
    float h  = a3 - a1 + 1.0f;
    float cx = a0 + 0.5f * w;
    float cy = a1 + 0.5f * h;
    float dwc = fminf(dw, BBOX_CLIP);
    float dhc = fminf(dh, BBOX_CLIP);
    float pcx = dx * w + cx;
    float pcy = dy * h + cy;
    float pw  = expf(dwc) * w;
    float ph  = expf(dhc) * h;
    float x1 = pcx - 0.5f * pw;
    float y1 = pcy - 0.5f * ph;
    float x2 = pcx + 0.5f * pw - 1.0f;
    float y2 = pcy + 0.5f * ph - 1.0f;
    x1 = fminf(fmaxf(x1, 0.0f), IMGMAX);
    y1 = fminf(fmaxf(y1, 0.0f), IMGMAX);
    x2 = fminf(fmaxf(x2, 0.0f), IMGMAX);
    y2 = fminf(fmaxf(y2, 0.0f), IMGMAX);
    bx1[gid] = x1; by1[gid] = y1; bx2[gid] = x2; by2[gid] = y2;
}

// =====================================================================
// K_iou: suppression-bit matrix. mat[n][row][w] bit j = IoU(row, 64w+j)>0.5
// Upper-triangle blocks only. grid: 16*64 blocks x 256 (4 waves).
// wave v of row-block R handles words w = R+v, R+v+4, ... ; lane = row.
// =====================================================================
__global__ __launch_bounds__(256) void k_iou(
        const float* __restrict__ bx1, const float* __restrict__ by1,
        const float* __restrict__ bx2, const float* __restrict__ by2,
        unsigned long long* __restrict__ mat) {
#pragma clang fp contract(off)
    const int n = blockIdx.x >> 6;
    const int R = blockIdx.x & 63;
    __shared__ float4 box[K1];                 // 64 KB
    const int tid = threadIdx.x;
    for (int t = tid; t < K1; t += 256) {
        float4 b;
        b.x = bx1[(size_t)n * K1 + t];
        b.y = by1[(size_t)n * K1 + t];
        b.z = bx2[(size_t)n * K1 + t];
        b.w = by2[(size_t)n * K1 + t];
        box[t] = b;
    }
    __syncthreads();
    const int lane = tid & 63, wv = tid >> 6;
    const int row = R * 64 + lane;
    const float4 q = box[row];
    const float qa = (q.z - q.x + 1.0f) * (q.w - q.y + 1.0f);
    for (int w = R + wv; w < 64; w += 4) {
        unsigned long long bits = 0ull;
        for (int j = 0; j < 64; ++j) {
            float4 b = box[w * 64 + j];        // wave-uniform -> LDS broadcast
            float ta = (b.z - b.x + 1.0f) * (b.w - b.y + 1.0f);
            float iw = fminf(q.z, b.z) - fmaxf(q.x, b.x) + 1.0f;
            float ih = fminf(q.w, b.w) - fmaxf(q.y, b.y) + 1.0f;
            iw = fmaxf(iw, 0.0f);
            ih = fmaxf(ih, 0.0f);
            float inter = iw * ih;
            float iou = inter / ((qa + ta) - inter);   // exact IEEE div, ref order
            if (iou > 0.5f) bits |= (1ull << j);
        }
        mat[((size_t)n * K1 + row) * 64 + w] = bits;
    }
}

// =====================================================================
// K_greedy: one wave per image; mask in registers; pipelined row window.
// =====================================================================
__global__ __launch_bounds__(64) void k_greedy(
        const unsigned long long* __restrict__ mat, int* __restrict__ skept) {
    const int n = blockIdx.x, lane = threadIdx.x;
    const unsigned long long* M = mat + (size_t)n * K1 * 64;
    int* kp = skept + n * K2;
    for (int k = lane; k < K2; k += 64) kp[k] = -1;

    unsigned long long rem = 0ull;
    int base = 0, cursor = 0;
    // A: rows base..base+7 (ready) ; B: rows base+8..base+15 (in flight)
    unsigned long long A0,A1,A2,A3,A4,A5,A6,A7, B0,B1,B2,B3,B4,B5,B6,B7;
    #define LD(r) M[(size_t)((r) < (K1-1) ? (r) : (K1-1)) * 64 + lane]
    A0=LD(0);A1=LD(1);A2=LD(2);A3=LD(3);A4=LD(4);A5=LD(5);A6=LD(6);A7=LD(7);
    B0=LD(8);B1=LD(9);B2=LD(10);B3=LD(11);B4=LD(12);B5=LD(13);B6=LD(14);B7=LD(15);

    for (int it = 0; it < K2; ++it) {
        const int cw = cursor >> 6;
        unsigned long long avail = ~rem;
        if (lane < cw) avail = 0ull;
        else if (lane == cw) avail &= ~((1ull << (cursor & 63)) - 1ull);
        unsigned long long bal = __ballot(avail != 0ull);
        if (bal == 0ull) break;
        const int L = __builtin_ctzll(bal);
        unsigned long long aL = __shfl(avail, L);
        const int c = (L << 6) + __builtin_ctzll(aL);
        if (lane == 0) kp[it] = c;

        const int d = c - base;                 // wave-uniform
        unsigned long long row;
        if      (d == 0) row = A0; else if (d == 1) row = A1;
        else if (d == 2) row = A2; else if (d == 3) row = A3;
        else if (d == 4) row = A4; else if (d == 5) row = A5;
        else if (d == 6) row = A6; else if (d == 7) row = A7;
        else row = M[(size_t)c * 64 + lane];    // rare: gap >= 8
        rem |= row;
        cursor = c + 1;

        if (cursor >= base + 16) {              // far jump: reset window
            base = cursor;
            A0=LD(base+0);A1=LD(base+1);A2=LD(base+2);A3=LD(base+3);
            A4=LD(base+4);A5=LD(base+5);A6=LD(base+6);A7=LD(base+7);
            B0=LD(base+8);B1=LD(base+9);B2=LD(base+10);B3=LD(base+11);
            B4=LD(base+12);B5=LD(base+13);B6=LD(base+14);B7=LD(base+15);
        } else if (cursor >= base + 8) {        // rotate: B (old, latency covered) -> A
            A0=B0;A1=B1;A2=B2;A3=B3;A4=B4;A5=B5;A6=B6;A7=B7;
            base += 8;
            B0=LD(base+8);B1=LD(base+9);B2=LD(base+10);B3=LD(base+11);
            B4=LD(base+12);B5=LD(base+13);B6=LD(base+14);B7=LD(base+15);
        }
    }
    #undef LD
}

// =====================================================================
// K_final: one wave per output row: class argmax (80 gathered) + write 6.
// grid: 1200 blocks x 256 (4800 waves).
// =====================================================================
__global__ __launch_bounds__(256) void k_final(
        const int* __restrict__ skept, const unsigned int* __restrict__ sidx,
        const float* __restrict__ sscore, const float* __restrict__ cls,
        const float* __restrict__ bx1, const float* __restrict__ by1,
        const float* __restrict__ bx2, const float* __restrict__ by2,
        float* __restrict__ out) {
    const int g = blockIdx.x * 4 + (threadIdx.x >> 6);   // [0, 4800)
    const int lane = threadIdx.x & 63;
    const int n = g / K2, k = g % K2;
    const int sel = skept[n * K2 + k];
    float* op = out + ((size_t)n * K2 + k) * 6;
    if (sel < 0) {
        if (lane < 6) op[lane] = 0.0f;
        return;
    }
    const unsigned int p = sidx[(size_t)n * K1 + sel];
    const int a  = (int)(p % 3u);
    const int hw = (int)(p / 3u);
    const float* cb = cls + ((size_t)n * 240 + a * 80) * HW_ + hw;
    float v = cb[(size_t)lane * HW_];
    int c = lane;
    if (lane < 16) {
        float v2 = cb[(size_t)(64 + lane) * HW_];
        if (v2 > v) { v = v2; c = 64 + lane; }   // tie keeps lower c
    }
    for (int off = 32; off > 0; off >>= 1) {
        float ov = __shfl_down(v, off);
        int   oc = __shfl_down(c, off);
        if ((ov > v) || (ov == v && oc < c)) { v = ov; c = oc; }
    }
    if (lane == 0) {
        op[0] = bx1[(size_t)n * K1 + sel];
        op[1] = by1[(size_t)n * K1 + sel];
        op[2] = bx2[(size_t)n * K1 + sel];
        op[3] = by2[(size_t)n * K1 + sel];
        op[4] = sscore[(size_t)n * K1 + sel];
        op[5] = (float)(c + 1);
    }
}

// =====================================================================
extern "C" void kernel_launch(void* const* d_in, const int* in_sizes, int n_in,
                              void* d_out, int out_size, void* d_ws, size_t ws_size,
                              hipStream_t stream) {
    (void)in_sizes; (void)n_in; (void)out_size; (void)ws_size;
    const float* objectness = (const float*)d_in[1];
    const float* box_reg    = (const float*)d_in[2];
    const float* cls        = (const float*)d_in[3];
    float* out = (float*)d_out;

    char* ws = (char*)d_ws;
    size_t off = 0;
    unsigned int* hist = (unsigned int*)(ws + off);       off += (size_t)NIMG * 4096 * 4; // 256 KB
    unsigned int* cnt  = (unsigned int*)(ws + off);       off += 64;
    unsigned int* Tarr = (unsigned int*)(ws + off);       off += 64;
    unsigned long long* cand = (unsigned long long*)(ws + off); off += (size_t)NIMG * CAND_CAP * 8;
    unsigned int* sidx = (unsigned int*)(ws + off);       off += (size_t)NIMG * K1 * 4;
    float* sscore = (float*)(ws + off);                   off += (size_t)NIMG * K1 * 4;
    float* bx1 = (float*)(ws + off);                      off += (size_t)NIMG * K1 * 4;
    float* by1 = (float*)(ws + off);                      off += (size_t)NIMG * K1 * 4;
    float* bx2 = (float*)(ws + off);                      off += (size_t)NIMG * K1 * 4;
    float* by2 = (float*)(ws + off);                      off += (size_t)NIMG * K1 * 4;
    unsigned long long* mat = (unsigned long long*)(ws + off); off += (size_t)NIMG * K1 * 64 * 8; // 32 MB
    int* skept = (int*)(ws + off);                        off += (size_t)NIMG * K2 * 4;
    // total ~36.5 MB

    hipMemsetAsync(hist, 0, (size_t)NIMG * 4096 * 4 + 64, stream);  // hist + cnt
    k_hist   <<<512, 256, 0, stream>>>(objectness, hist);
    k_thresh <<<NIMG, 64, 0, stream>>>(hist, Tarr);
    k_compact<<<NIMG * 75, 1024, 0, stream>>>(objectness, Tarr, cand, cnt);
    k_sort   <<<NIMG, 1024, 0, stream>>>(cand, cnt, sidx, sscore);
    k_decode <<<(NIMG * K1) / 256, 256, 0, stream>>>(sidx, box_reg, bx1, by1, bx2, by2);
    k_iou    <<<NIMG * 64, 256, 0, stream>>>(bx1, by1, bx2, by2, mat);
    k_greedy <<<NIMG, 64, 0, stream>>>(mat, skept);
    k_final  <<<NIMG * K2 / 4, 256, 0, stream>>>(skept, sidx, sscore, cls,
                                                 bx1, by1, bx2, by2, out);
}

// Round 3
// 811.960 us; speedup vs baseline: 1.6098x; 1.6098x over previous
//
#include <hip/hip_runtime.h>
#include <math.h>

#define NIMG 16
#define A_ 3
#define H_ 160
#define W_ 160
#define C_ 80
#define HW_ (H_*W_)        // 25600
#define P_ (HW_*A_)        // 76800
#define K1 4096
#define K2 300
#define CAND_CAP 8192
#define IMGMAX 639.0f
#define BBOX_CLIP 4.135166556742356f  // log(1000/16)
// 0.5 + 2^-26, exact in double. RN32(inter/denom) > 0.5  <=>  denom>0 && inter > denom*THR (exact)
#define IOU_THR (0.5 + 1.0/67108864.0)

__device__ __forceinline__ unsigned int f2key(float x) {
    unsigned int u = __float_as_uint(x);
    return (u & 0x80000000u) ? ~u : (u | 0x80000000u);
}
__device__ __forceinline__ float key2f(unsigned int k) {
    unsigned int u = (k & 0x80000000u) ? (k & 0x7FFFFFFFu) : ~k;
    return __uint_as_float(u);
}

// =====================================================================
// S1: per-image histogram of top-12 key bits, LDS-aggregated.
// grid: 240 blocks x 256 (15 blocks/image, 5120 items each)
// =====================================================================
__global__ __launch_bounds__(256) void k_hist(
        const float* __restrict__ obj, unsigned int* __restrict__ hist) {
    const int n = blockIdx.x / 15;
    const int chunk = blockIdx.x % 15;
    __shared__ unsigned int lh[4096];
    const int tid = threadIdx.x;
    for (int i = tid; i < 4096; i += 256) lh[i] = 0;
    __syncthreads();
    const float* o = obj + (size_t)n * P_ + chunk * 5120;
    for (int q = tid; q < 5120; q += 256) {
        unsigned int k = f2key(o[q]);
        atomicAdd(&lh[k >> 20], 1u);
    }
    __syncthreads();
    for (int i = tid; i < 4096; i += 256) {
        unsigned int v = lh[i];
        if (v) atomicAdd(&hist[n * 4096 + i], v);
    }
}

// =====================================================================
// S2: per-image threshold bucket via wave suffix-scan. 16 blocks x 64.
// =====================================================================
__global__ __launch_bounds__(64) void k_thresh(
        const unsigned int* __restrict__ hist, unsigned int* __restrict__ Tarr) {
    const int n = blockIdx.x, lane = threadIdx.x;
    const unsigned int* h = hist + n * 4096;
    unsigned int s = 0;
    for (int m = 0; m < 64; ++m) s += h[lane * 64 + m];
    unsigned int t = s;
    for (int off = 1; off < 64; off <<= 1) {
        unsigned int u = __shfl_down(t, off);
        if (lane + off < 64) t += u;
    }
    bool cond = (t >= (unsigned)K1) && (t - s < (unsigned)K1);
    unsigned long long bal = __ballot(cond);
    int cs = __builtin_ctzll(bal);
    unsigned int suf = __shfl(t - s, cs);
    unsigned int h2 = h[cs * 64 + lane];
    unsigned int t2 = h2;
    for (int off = 1; off < 64; off <<= 1) {
        unsigned int u = __shfl_down(t2, off);
        if (lane + off < 64) t2 += u;
    }
    bool cond2 = (suf + t2 >= (unsigned)K1) && (suf + t2 - h2 < (unsigned)K1);
    if (cond2) Tarr[n] = ((unsigned int)(cs * 64 + lane)) << 20;
}

// =====================================================================
// S3: compaction, block-aggregated atomics (1 global RMW per block).
// grid: 1200 blocks x 1024
// =====================================================================
__global__ __launch_bounds__(1024) void k_compact(
        const float* __restrict__ obj, const unsigned int* __restrict__ Tarr,
        unsigned long long* __restrict__ cand, unsigned int* __restrict__ cnt) {
    const int n = blockIdx.x / 75;
    const int q = (blockIdx.x % 75) * 1024 + threadIdx.x;
    const unsigned int T = Tarr[n];
    unsigned int k = f2key(obj[(size_t)n * P_ + q]);
    bool pred = (k >= T);
    const int lane = threadIdx.x & 63, wv = threadIdx.x >> 6;
    unsigned long long m = __ballot(pred);
    __shared__ unsigned int s_wbase[16];
    __shared__ unsigned int s_cnt, s_start;
    if (threadIdx.x == 0) s_cnt = 0;
    __syncthreads();
    if (lane == 0) s_wbase[wv] = atomicAdd(&s_cnt, (unsigned int)__popcll(m));
    __syncthreads();
    if (threadIdx.x == 0) s_start = atomicAdd(&cnt[n], s_cnt);
    __syncthreads();
    if (pred) {
        unsigned int pos = s_start + s_wbase[wv] +
                           (unsigned int)__popcll(m & ((1ull << lane) - 1ull));
        if (pos < CAND_CAP) {
            unsigned int p = (unsigned int)((q % HW_) * A_ + (q / HW_));
            cand[(size_t)n * CAND_CAP + pos] =
                ((unsigned long long)(~k) << 32) | (unsigned long long)p;
        }
    }
}

// =====================================================================
// K_sort: segment-mapped bitonic. Wave w owns items [512w, 512w+512);
// stages with j<512 are wave-local (no barrier). 16 blocks x 1024.
// =====================================================================
__global__ __launch_bounds__(1024) void k_sort(
        const unsigned long long* __restrict__ cand,
        const unsigned int* __restrict__ cnt,
        unsigned int* __restrict__ sidx, float* __restrict__ sscore) {
    const int n = blockIdx.x;
    __shared__ unsigned long long S[CAND_CAP];   // 64 KB
    const int tid = threadIdx.x;
    const int wv = tid >> 6, lane = tid & 63;
    const int seg = wv * 512;
    unsigned int c = cnt[n]; if (c > CAND_CAP) c = CAND_CAP;
    #pragma unroll
    for (int m = 0; m < 8; ++m) {
        int t = seg + m * 64 + lane;
        S[t] = (t < (int)c) ? cand[(size_t)n * CAND_CAP + t] : 0xFFFFFFFFFFFFFFFFull;
    }
    int prevCross = 1;   // force barrier at first stage (covers load visibility)
    for (int k = 2; k <= CAND_CAP; k <<= 1) {
        for (int j = k >> 1; j > 0; j >>= 1) {
            int cross = (j >= 512);
            if (cross || prevCross) __syncthreads();
            #pragma unroll
            for (int m = 0; m < 8; ++m) {
                int t = seg + m * 64 + lane;
                int ixj = t ^ j;
                if (ixj > t) {
                    unsigned long long a = S[t], b = S[ixj];
                    bool up = ((t & k) == 0);
                    if ((a > b) == up) { S[t] = b; S[ixj] = a; }
                }
            }
            prevCross = cross;
        }
    }
    if (wv < 8) {
        #pragma unroll
        for (int m = 0; m < 8; ++m) {
            int t = seg + m * 64 + lane;
            unsigned long long s = S[t];
            sidx[(size_t)n * K1 + t] = (unsigned int)s;
            float x = key2f(~(unsigned int)(s >> 32));
            sscore[(size_t)n * K1 + t] = 1.0f / (1.0f + expf(-x));
        }
    }
}

// =====================================================================
// K_decode: analytic anchors + decode + clip + area. 256 blocks x 256.
// =====================================================================
__global__ __launch_bounds__(256) void k_decode(
        const unsigned int* __restrict__ sidx, const float* __restrict__ reg,
        float* __restrict__ bx1, float* __restrict__ by1,
        float* __restrict__ bx2, float* __restrict__ by2,
        float* __restrict__ bar) {
#pragma clang fp contract(off)
    const int gid = blockIdx.x * 256 + threadIdx.x;
    const int n = gid >> 12;
    const unsigned int p = sidx[gid];
    const int a  = (int)(p % 3u);
    const int hw = (int)(p / 3u);
    const int hh = hw / W_, ww = hw % W_;

    const float* rb = reg + ((size_t)n * 12 + a * 4) * HW_ + hw;
    float dx = rb[0];
    float dy = rb[HW_];
    float dw = rb[2 * HW_];
    float dh = rb[3 * HW_];

    const int half = 16 << a;
    float a0 = (float)(4 * ww + 2 - half);
    float a1 = (float)(4 * hh + 2 - half);
    float a2 = (float)(4 * ww + 2 + half - 1);
    float a3 = (float)(4 * hh + 2 + half - 1);

    float w  = a2 - a0 + 1.0f;
    float h  = a3 - a1 + 1.0f;
    float cx = a0 + 0.5f * w;
    float cy = a1 + 0.5f * h;
    float dwc = fminf(dw, BBOX_CLIP);
    float dhc = fminf(dh, BBOX_CLIP);
    float pcx = dx * w + cx;
    float pcy = dy * h + cy;
    float pw  = expf(dwc) * w;
    float ph  = expf(dhc) * h;
    float x1 = pcx - 0.5f * pw;
    float y1 = pcy - 0.5f * ph;
    float x2 = pcx + 0.5f * pw - 1.0f;
    float y2 = pcy + 0.5f * ph - 1.0f;
    x1 = fminf(fmaxf(x1, 0.0f), IMGMAX);
    y1 = fminf(fmaxf(y1, 0.0f), IMGMAX);
    x2 = fminf(fmaxf(x2, 0.0f), IMGMAX);
    y2 = fminf(fmaxf(y2, 0.0f), IMGMAX);
    bx1[gid] = x1; by1[gid] = y1; bx2[gid] = x2; by2[gid] = y2;
    bar[gid] = (x2 - x1 + 1.0f) * (y2 - y1 + 1.0f);   // reference area order
}

// =====================================================================
// K_iou: one 64x64 tile per wave. Block = (n, R, word-quad); wave v
// handles word w = quad*4+v (skip if w < R). 5 KB LDS. Exact-equivalent
// double compare replaces fp32 division.
// grid: 16*64*16 = 16384 blocks x 256
// =====================================================================
__global__ __launch_bounds__(256) void k_iou(
        const float* __restrict__ bx1, const float* __restrict__ by1,
        const float* __restrict__ bx2, const float* __restrict__ by2,
        const float* __restrict__ bar,
        unsigned long long* __restrict__ mat) {
#pragma clang fp contract(off)
    const int b = blockIdx.x;
    const int n = b >> 10;
    const int R = (b >> 4) & 63;
    const int quad = b & 15;
    const int tid = threadIdx.x, lane = tid & 63, wv = tid >> 6;
    __shared__ float4 cbox[256];
    __shared__ float  carea[256];
    const int wcol = quad * 4 + wv;
    {
        int col = wcol * 64 + lane;
        float4 v;
        v.x = bx1[(size_t)n * K1 + col];
        v.y = by1[(size_t)n * K1 + col];
        v.z = bx2[(size_t)n * K1 + col];
        v.w = by2[(size_t)n * K1 + col];
        cbox[tid] = v;
        carea[tid] = bar[(size_t)n * K1 + col];
    }
    const int row = R * 64 + lane;
    const float qx1 = bx1[(size_t)n * K1 + row];
    const float qy1 = by1[(size_t)n * K1 + row];
    const float qx2 = bx2[(size_t)n * K1 + row];
    const float qy2 = by2[(size_t)n * K1 + row];
    const float qa  = bar[(size_t)n * K1 + row];
    __syncthreads();
    if (wcol < R) return;
    unsigned long long bits = 0ull;
    const int basec = wv * 64;
    #pragma unroll 8
    for (int j = 0; j < 64; ++j) {
        float4 bb = cbox[basec + j];
        float ta = carea[basec + j];
        float iw = fminf(qx2, bb.z) - fmaxf(qx1, bb.x) + 1.0f;
        float ih = fminf(qy2, bb.w) - fmaxf(qy1, bb.y) + 1.0f;
        iw = fmaxf(iw, 0.0f);
        ih = fmaxf(ih, 0.0f);
        float inter = iw * ih;
        float denom = (qa + ta) - inter;   // reference op order
        if (denom > 0.0f && (double)inter > (double)denom * IOU_THR)
            bits |= (1ull << j);
    }
    mat[((size_t)n * K1 + row) * 64 + wcol] = bits;
}

// =====================================================================
// K_greedy: producer-consumer. Wave 0 picks (barrier-free), wave 1
// streams rows into a 128-row LDS ring ahead of the cursor.
// grid: 16 blocks x 128
// =====================================================================
__global__ __launch_bounds__(128) void k_greedy(
        const unsigned long long* __restrict__ mat, int* __restrict__ skept) {
    const int n = blockIdx.x;
    const unsigned long long* M = mat + (size_t)n * K1 * 64;
    int* kp = skept + n * K2;
    const int tid = threadIdx.x, lane = tid & 63, wv = tid >> 6;
    __shared__ unsigned long long ring[128 * 64];   // 64 KB
    __shared__ int ctl[3];                          // 0: cursor hint, 1: loaded, 2: done
    volatile int* vctl = ctl;
    for (int k = tid; k < K2; k += 128) kp[k] = -1;
    if (tid == 0) { ctl[0] = 0; ctl[1] = 0; ctl[2] = 0; }
    __syncthreads();

    if (wv == 1) {
        int loaded = 0;
        while (!vctl[2] && loaded < K1) {
            int hint = vctl[0];
            int tgt = hint + 128; if (tgt > K1) tgt = K1;   // rows < tgt; never touches slot of row `hint`
            if (loaded < tgt) {
                int batch = tgt - loaded; if (batch > 16) batch = 16;
                unsigned long long tmp[16];
                #pragma unroll
                for (int i = 0; i < 16; ++i)
                    tmp[i] = (i < batch) ? M[(size_t)(loaded + i) * 64 + lane] : 0ull;
                #pragma unroll
                for (int i = 0; i < 16; ++i)
                    if (i < batch) ring[((loaded + i) & 127) * 64 + lane] = tmp[i];
                __asm__ __volatile__("s_waitcnt lgkmcnt(0)" ::: "memory");  // release
                loaded += batch;
                vctl[1] = loaded;
            } else {
                __builtin_amdgcn_s_sleep(1);
            }
        }
    } else {
        unsigned long long rem = 0ull;
        int cursor = 0;
        for (int it = 0; it < K2; ++it) {
            const int cw = cursor >> 6;
            unsigned long long avail = ~rem;
            if (lane < cw) avail = 0ull;
            else if (lane == cw) avail &= ~((1ull << (cursor & 63)) - 1ull);
            unsigned long long bal = __ballot(avail != 0ull);
            if (bal == 0ull) break;
            const int L = (int)__builtin_ctzll(bal);
            unsigned long long aL = __shfl(avail, L);
            const int c = (L << 6) + (int)__builtin_ctzll(aL);
            if (lane == 0) { kp[it] = c; vctl[0] = c; }
            while (vctl[1] <= c) __builtin_amdgcn_s_sleep(1);   // acquire
            __asm__ __volatile__("" ::: "memory");
            rem |= ring[(c & 127) * 64 + lane];
            cursor = c + 1;
        }
        if (lane == 0) vctl[2] = 1;
    }
}

// =====================================================================
// K_final: one wave per output row: class argmax (80 gathered) + write 6.
// grid: 1200 blocks x 256
// =====================================================================
__global__ __launch_bounds__(256) void k_final(
        const int* __restrict__ skept, const unsigned int* __restrict__ sidx,
        const float* __restrict__ sscore, const float* __restrict__ cls,
        const float* __restrict__ bx1, const float* __restrict__ by1,
        const float* __restrict__ bx2, const float* __restrict__ by2,
        float* __restrict__ out) {
    const int g = blockIdx.x * 4 + (threadIdx.x >> 6);
    const int lane = threadIdx.x & 63;
    const int n = g / K2, k = g % K2;
    const int sel = skept[n * K2 + k];
    float* op = out + ((size_t)n * K2 + k) * 6;
    if (sel < 0) {
        if (lane < 6) op[lane] = 0.0f;
        return;
    }
    const unsigned int p = sidx[(size_t)n * K1 + sel];
    const int a  = (int)(p % 3u);
    const int hw = (int)(p / 3u);
    const float* cb = cls + ((size_t)n * 240 + a * 80) * HW_ + hw;
    float v = cb[(size_t)lane * HW_];
    int c = lane;
    if (lane < 16) {
        float v2 = cb[(size_t)(64 + lane) * HW_];
        if (v2 > v) { v = v2; c = 64 + lane; }
    }
    for (int off = 32; off > 0; off >>= 1) {
        float ov = __shfl_down(v, off);
        int   oc = __shfl_down(c, off);
        if ((ov > v) || (ov == v && oc < c)) { v = ov; c = oc; }
    }
    if (lane == 0) {
        op[0] = bx1[(size_t)n * K1 + sel];
        op[1] = by1[(size_t)n * K1 + sel];
        op[2] = bx2[(size_t)n * K1 + sel];
        op[3] = by2[(size_t)n * K1 + sel];
        op[4] = sscore[(size_t)n * K1 + sel];
        op[5] = (float)(c + 1);
    }
}

// =====================================================================
extern "C" void kernel_launch(void* const* d_in, const int* in_sizes, int n_in,
                              void* d_out, int out_size, void* d_ws, size_t ws_size,
                              hipStream_t stream) {
    (void)in_sizes; (void)n_in; (void)out_size; (void)ws_size;
    const float* objectness = (const float*)d_in[1];
    const float* box_reg    = (const float*)d_in[2];
    const float* cls        = (const float*)d_in[3];
    float* out = (float*)d_out;

    char* ws = (char*)d_ws;
    size_t off = 0;
    unsigned int* hist = (unsigned int*)(ws + off);       off += (size_t)NIMG * 4096 * 4;
    unsigned int* cnt  = (unsigned int*)(ws + off);       off += 64;
    unsigned int* Tarr = (unsigned int*)(ws + off);       off += 64;
    unsigned long long* cand = (unsigned long long*)(ws + off); off += (size_t)NIMG * CAND_CAP * 8;
    unsigned int* sidx = (unsigned int*)(ws + off);       off += (size_t)NIMG * K1 * 4;
    float* sscore = (float*)(ws + off);                   off += (size_t)NIMG * K1 * 4;
    float* bx1 = (float*)(ws + off);                      off += (size_t)NIMG * K1 * 4;
    float* by1 = (float*)(ws + off);                      off += (size_t)NIMG * K1 * 4;
    float* bx2 = (float*)(ws + off);                      off += (size_t)NIMG * K1 * 4;
    float* by2 = (float*)(ws + off);                      off += (size_t)NIMG * K1 * 4;
    float* bar = (float*)(ws + off);                      off += (size_t)NIMG * K1 * 4;
    unsigned long long* mat = (unsigned long long*)(ws + off); off += (size_t)NIMG * K1 * 64 * 8;
    int* skept = (int*)(ws + off);                        off += (size_t)NIMG * K2 * 4;

    hipMemsetAsync(hist, 0, (size_t)NIMG * 4096 * 4 + 64, stream);  // hist + cnt
    k_hist   <<<240, 256, 0, stream>>>(objectness, hist);
    k_thresh <<<NIMG, 64, 0, stream>>>(hist, Tarr);
    k_compact<<<NIMG * 75, 1024, 0, stream>>>(objectness, Tarr, cand, cnt);
    k_sort   <<<NIMG, 1024, 0, stream>>>(cand, cnt, sidx, sscore);
    k_decode <<<(NIMG * K1) / 256, 256, 0, stream>>>(sidx, box_reg, bx1, by1, bx2, by2, bar);
    k_iou    <<<NIMG * 64 * 16, 256, 0, stream>>>(bx1, by1, bx2, by2, bar, mat);
    k_greedy <<<NIMG, 128, 0, stream>>>(mat, skept);
    k_final  <<<NIMG * K2 / 4, 256, 0, stream>>>(skept, sidx, sscore, cls,
                                                 bx1, by1, bx2, by2, out);
}